// Round 1
// baseline (304.621 us; speedup 1.0000x reference)
//
#include <hip/hip_runtime.h>
#include <hip/hip_bf16.h>

// GAT layer: B=32, N=1024, IN_F=OUT_F=256, alpha=0.2
// Pipeline:
//  K1: WhT[b][o][n] = bf16( sum_i h[b,n,i]*W[o,i] )  (MFMA bf16, fp32 acc)
//  K2: si[b,n] = sum_o WhT*a1[o]; sj likewise with a2
//  K3: fused masked-softmax attention + PV matmul + ELU (flash-style, no
//      NxN materialization; softmax without max-subtraction is safe here)

#define ALPHA 0.2f

typedef __bf16 bf16x8 __attribute__((ext_vector_type(8)));
typedef __bf16 bf16x4 __attribute__((ext_vector_type(4)));
typedef float  f32x4  __attribute__((ext_vector_type(4)));

// ---------------- K1: Wh = h @ W^T, stored transposed as bf16 ----------------
// grid 512 blocks x 256 thr; block = 64 rows x 256 cols, K chunks of 64.
__global__ __launch_bounds__(256) void k1_gemm1(const float* __restrict__ h,
                                                const float* __restrict__ W,
                                                __bf16* __restrict__ whT) {
    __shared__ __bf16 hA[64 * 72];    // pad 64->72 elems (144B, 16B-aligned, 2-way banks)
    __shared__ __bf16 hB[256 * 72];
    const int t    = threadIdx.x;
    const int r0   = blockIdx.x * 64;         // global row in [0, 32768)
    const int b    = r0 >> 10;
    const int n0   = r0 & 1023;
    const int w    = t >> 6;                  // wave id 0..3 -> o range [64w,64w+64)
    const int l    = t & 63;
    const int ln   = l & 15;
    const int quad = l >> 4;

    f32x4 acc[4][4] = {};

    for (int kc = 0; kc < 4; ++kc) {
        const int k0 = kc * 64;
        // stage h tile: 64 rows x 64 k (fp32 -> bf16)
        #pragma unroll
        for (int it = 0; it < 4; ++it) {
            const int row = it * 16 + (t >> 4);
            const int seg = t & 15;
            const float4 v = *(const float4*)&h[(size_t)(r0 + row) * 256 + k0 + seg * 4];
            bf16x4 pv = {(__bf16)v.x, (__bf16)v.y, (__bf16)v.z, (__bf16)v.w};
            *(bf16x4*)&hA[row * 72 + seg * 4] = pv;
        }
        // stage W tile: 256 rows x 64 k
        #pragma unroll
        for (int it = 0; it < 16; ++it) {
            const int o   = it * 16 + (t >> 4);
            const int seg = t & 15;
            const float4 v = *(const float4*)&W[(size_t)o * 256 + k0 + seg * 4];
            bf16x4 pv = {(__bf16)v.x, (__bf16)v.y, (__bf16)v.z, (__bf16)v.w};
            *(bf16x4*)&hB[o * 72 + seg * 4] = pv;
        }
        __syncthreads();
        #pragma unroll
        for (int kk = 0; kk < 2; ++kk) {
            bf16x8 af[4], bfr[4];
            #pragma unroll
            for (int ri = 0; ri < 4; ++ri)
                af[ri] = *(const bf16x8*)&hA[(ri * 16 + ln) * 72 + kk * 32 + quad * 8];
            #pragma unroll
            for (int oi = 0; oi < 4; ++oi)
                bfr[oi] = *(const bf16x8*)&hB[(w * 64 + oi * 16 + ln) * 72 + kk * 32 + quad * 8];
            #pragma unroll
            for (int ri = 0; ri < 4; ++ri)
                #pragma unroll
                for (int oi = 0; oi < 4; ++oi)
                    acc[ri][oi] = __builtin_amdgcn_mfma_f32_16x16x32_bf16(
                        af[ri], bfr[oi], acc[ri][oi], 0, 0, 0);
        }
        __syncthreads();
    }
    // epilogue: WhT[b][o][n] bf16, pack 4 consecutive n (the 4 acc regs)
    #pragma unroll
    for (int ri = 0; ri < 4; ++ri) {
        const int n = n0 + ri * 16 + quad * 4;
        #pragma unroll
        for (int oi = 0; oi < 4; ++oi) {
            const int o = w * 64 + oi * 16 + ln;
            bf16x4 pv = {(__bf16)acc[ri][oi][0], (__bf16)acc[ri][oi][1],
                         (__bf16)acc[ri][oi][2], (__bf16)acc[ri][oi][3]};
            *(bf16x4*)&whT[((size_t)b * 256 + o) * 1024 + n] = pv;
        }
    }
}

// ---------------- K2: si/sj from WhT ----------------
__global__ __launch_bounds__(256) void k2_scores(const __bf16* __restrict__ whT,
                                                 const float* __restrict__ a,
                                                 float* __restrict__ si,
                                                 float* __restrict__ sj) {
    const int tid = blockIdx.x * 256 + threadIdx.x;   // [0, 32768)
    const int b = tid >> 10, n = tid & 1023;
    const __bf16* base = whT + (size_t)b * 256 * 1024 + n;
    float s1 = 0.f, s2 = 0.f;
    #pragma unroll 8
    for (int o = 0; o < 256; ++o) {
        const float v = (float)base[(size_t)o * 1024];
        s1 += v * a[o];
        s2 += v * a[256 + o];
    }
    si[tid] = s1;
    sj[tid] = s2;
}

// ---------------- K3: fused attention ----------------
// grid (16, 32): x = i-tile (64 rows), y = batch. 256 thr (4 waves).
__global__ __launch_bounds__(256) void k3_attn(const int* __restrict__ adj,
                                               const __bf16* __restrict__ whT,
                                               const float* __restrict__ si_g,
                                               const float* __restrict__ sj_g,
                                               float* __restrict__ out) {
    __shared__ __bf16 lds_w[256 * 72];   // WhT chunk: [o][j_local], padded
    __shared__ __bf16 lds_s[64 * 72];    // S tile: [i_local][j_local], padded
    __shared__ float  lds_denom[64];
    const int t    = threadIdx.x;
    const int b    = blockIdx.y;
    const int i0   = blockIdx.x * 64;
    const int w    = t >> 6;
    const int l    = t & 63;
    const int ln   = l & 15;
    const int quad = l >> 4;
    const int g    = t >> 4;   // 0..15
    const int j4   = t & 15;   // 0..15

    float si_r[4];
    #pragma unroll
    for (int m = 0; m < 4; ++m) si_r[m] = si_g[b * 1024 + i0 + m * 16 + g];

    float dsum[4] = {0.f, 0.f, 0.f, 0.f};
    f32x4 acc[4][4] = {};
    const __bf16* whTb = whT + (size_t)b * 256 * 1024;

    for (int jc = 0; jc < 16; ++jc) {
        const int j0 = jc * 64;
        // stage WhT chunk: 256 o-rows x 64 j
        #pragma unroll
        for (int it = 0; it < 8; ++it) {
            const int o   = it * 32 + (t >> 3);
            const int seg = t & 7;
            const bf16x8 v = *(const bf16x8*)&whTb[(size_t)o * 1024 + j0 + seg * 8];
            *(bf16x8*)&lds_w[o * 72 + seg * 8] = v;
        }
        // elementwise: w = adj ? exp(leakyrelu(si+sj)) : 0, write bf16 S tile
        #pragma unroll
        for (int m = 0; m < 4; ++m) {
            const int il = m * 16 + g;
            const int i  = i0 + il;
            const int jb = j0 + j4 * 4;
            const int4   a4 = *(const int4*)&adj[((size_t)(b * 1024 + i)) * 1024 + jb];
            const float4 s4 = *(const float4*)&sj_g[b * 1024 + jb];
            float e0 = si_r[m] + s4.x; e0 = e0 > 0.f ? e0 : ALPHA * e0;
            float e1 = si_r[m] + s4.y; e1 = e1 > 0.f ? e1 : ALPHA * e1;
            float e2 = si_r[m] + s4.z; e2 = e2 > 0.f ? e2 : ALPHA * e2;
            float e3 = si_r[m] + s4.w; e3 = e3 > 0.f ? e3 : ALPHA * e3;
            const float w0 = a4.x > 0 ? __expf(e0) : 0.f;
            const float w1 = a4.y > 0 ? __expf(e1) : 0.f;
            const float w2 = a4.z > 0 ? __expf(e2) : 0.f;
            const float w3 = a4.w > 0 ? __expf(e3) : 0.f;
            bf16x4 pv = {(__bf16)w0, (__bf16)w1, (__bf16)w2, (__bf16)w3};
            // denominator from the bf16-rounded weights (consistent w/ numerator)
            dsum[m] += (float)pv[0] + (float)pv[1] + (float)pv[2] + (float)pv[3];
            *(bf16x4*)&lds_s[il * 72 + j4 * 4] = pv;
        }
        __syncthreads();
        // P(64x64) @ Wh(64x256)
        #pragma unroll
        for (int kk = 0; kk < 2; ++kk) {
            bf16x8 af[4], bfr[4];
            #pragma unroll
            for (int ri = 0; ri < 4; ++ri)
                af[ri] = *(const bf16x8*)&lds_s[(ri * 16 + ln) * 72 + kk * 32 + quad * 8];
            #pragma unroll
            for (int oi = 0; oi < 4; ++oi)
                bfr[oi] = *(const bf16x8*)&lds_w[(w * 64 + oi * 16 + ln) * 72 + kk * 32 + quad * 8];
            #pragma unroll
            for (int ri = 0; ri < 4; ++ri)
                #pragma unroll
                for (int oi = 0; oi < 4; ++oi)
                    acc[ri][oi] = __builtin_amdgcn_mfma_f32_16x16x32_bf16(
                        af[ri], bfr[oi], acc[ri][oi], 0, 0, 0);
        }
        __syncthreads();
    }
    // reduce denominators across the 16 j4 lanes sharing each row
    #pragma unroll
    for (int m = 0; m < 4; ++m) {
        float v = dsum[m];
        v += __shfl_xor(v, 1);
        v += __shfl_xor(v, 2);
        v += __shfl_xor(v, 4);
        v += __shfl_xor(v, 8);
        if (j4 == 0) lds_denom[m * 16 + g] = v;
    }
    __syncthreads();
    // epilogue: normalize, ELU, store
    #pragma unroll
    for (int ri = 0; ri < 4; ++ri) {
        #pragma unroll
        for (int q = 0; q < 4; ++q) {
            const int il = ri * 16 + quad * 4 + q;
            const float dinv = 1.0f / fmaxf(lds_denom[il], 1e-30f);
            #pragma unroll
            for (int oi = 0; oi < 4; ++oi) {
                const int o = w * 64 + oi * 16 + ln;
                const float v = acc[ri][oi][q] * dinv;
                const float r = v > 0.f ? v : __expf(v) - 1.f;
                out[((size_t)(b * 1024 + i0 + il)) * 256 + o] = r;
            }
        }
    }
}

extern "C" void kernel_launch(void* const* d_in, const int* in_sizes, int n_in,
                              void* d_out, int out_size, void* d_ws, size_t ws_size,
                              hipStream_t stream) {
    const float* h   = (const float*)d_in[0];
    const int*   adj = (const int*)d_in[1];
    const float* W   = (const float*)d_in[2];
    const float* a   = (const float*)d_in[3];
    float* out = (float*)d_out;

    __bf16* whT = (__bf16*)d_ws;                              // 32*256*1024*2B = 16 MiB
    float*  si  = (float*)((char*)d_ws + (size_t)16777216);   // 32768 f32
    float*  sj  = si + 32768;                                 // 32768 f32

    k1_gemm1<<<512, 256, 0, stream>>>(h, W, whT);
    k2_scores<<<128, 256, 0, stream>>>(whT, a, si, sj);
    k3_attn<<<dim3(16, 32), 256, 0, stream>>>(adj, whT, si, sj, out);
}

// Round 2
// 286.283 us; speedup vs baseline: 1.0641x; 1.0641x over previous
//
#include <hip/hip_runtime.h>
#include <hip/hip_bf16.h>

// GAT layer: B=32, N=1024, IN_F=OUT_F=256, alpha=0.2
//  k0: adj (int32, 134 MB) -> packed bitmask (u64 per 64-j chunk, 4 MB), ballot
//  k1: WhT[b][o][n] = bf16(h @ W^T), MFMA; epilogue via LDS -> coalesced 128B
//      row-segment writes; fused si/sj (= Wh @ a1/a2) computation
//  k3: fused masked-softmax attention + PV MFMA + ELU, software-pipelined
//      (reg-prefetch of whT chunk + mask + sj across the MFMA section)

#define ALPHA 0.2f

typedef __bf16 bf16x8 __attribute__((ext_vector_type(8)));
typedef __bf16 bf16x4 __attribute__((ext_vector_type(4)));
typedef float  f32x4  __attribute__((ext_vector_type(4)));
typedef unsigned long long u64;

// ---------------- k0: adj -> bitmask ----------------
// 524288 words total; 2048 blocks x 256 thr = 8192 waves x 64 words each.
__global__ __launch_bounds__(256) void k0_mask(const int* __restrict__ adj,
                                               u64* __restrict__ mask) {
    const int wid = (blockIdx.x * 256 + threadIdx.x) >> 6;  // 0..8191
    const int l   = threadIdx.x & 63;
    const size_t base = (size_t)wid * 64;
    #pragma unroll 4
    for (int it = 0; it < 64; ++it) {
        const size_t word = base + it;
        const int v = adj[word * 64 + l];
        const u64 m = __ballot(v > 0);
        if (l == 0) mask[word] = m;
    }
}

// ---------------- k1: Wh = h @ W^T -> whT (bf16) + si/sj ----------------
// grid 512 x 256 thr; block = 64 n-rows x 256 o, K chunks of 64, reg-prefetched.
__global__ __launch_bounds__(256) void k1_gemm1(const float* __restrict__ h,
                                                const float* __restrict__ W,
                                                const float* __restrict__ a_g,
                                                __bf16* __restrict__ whT,
                                                float* __restrict__ si,
                                                float* __restrict__ sj) {
    __shared__ __bf16 hA[64 * 72];
    __shared__ __bf16 hB[256 * 72];   // W tiles; reused as [o][n] out-staging
    __shared__ float  red[512];
    const int t    = threadIdx.x;
    const int r0   = blockIdx.x * 64;
    const int b    = r0 >> 10;
    const int n0   = r0 & 1023;
    const int w    = t >> 6;
    const int l    = t & 63;
    const int ln   = l & 15;
    const int quad = l >> 4;

    f32x4 acc[4][4] = {};
    float4 ha_r[4], wb_r[16];

    // preload chunk 0
    #pragma unroll
    for (int it = 0; it < 4; ++it)
        ha_r[it] = *(const float4*)&h[(size_t)(r0 + it * 16 + (t >> 4)) * 256 + (t & 15) * 4];
    #pragma unroll
    for (int it = 0; it < 16; ++it)
        wb_r[it] = *(const float4*)&W[(size_t)(it * 16 + (t >> 4)) * 256 + (t & 15) * 4];

    for (int kc = 0; kc < 4; ++kc) {
        // write staged chunk to LDS (fp32 -> bf16)
        #pragma unroll
        for (int it = 0; it < 4; ++it) {
            const float4 v = ha_r[it];
            bf16x4 pv = {(__bf16)v.x, (__bf16)v.y, (__bf16)v.z, (__bf16)v.w};
            *(bf16x4*)&hA[(it * 16 + (t >> 4)) * 72 + (t & 15) * 4] = pv;
        }
        #pragma unroll
        for (int it = 0; it < 16; ++it) {
            const float4 v = wb_r[it];
            bf16x4 pv = {(__bf16)v.x, (__bf16)v.y, (__bf16)v.z, (__bf16)v.w};
            *(bf16x4*)&hB[(it * 16 + (t >> 4)) * 72 + (t & 15) * 4] = pv;
        }
        __syncthreads();
        // prefetch next chunk while MFMA runs
        if (kc < 3) {
            const int k0 = (kc + 1) * 64;
            #pragma unroll
            for (int it = 0; it < 4; ++it)
                ha_r[it] = *(const float4*)&h[(size_t)(r0 + it * 16 + (t >> 4)) * 256 + k0 + (t & 15) * 4];
            #pragma unroll
            for (int it = 0; it < 16; ++it)
                wb_r[it] = *(const float4*)&W[(size_t)(it * 16 + (t >> 4)) * 256 + k0 + (t & 15) * 4];
        }
        #pragma unroll
        for (int kk = 0; kk < 2; ++kk) {
            bf16x8 af[4], bfr[4];
            #pragma unroll
            for (int ri = 0; ri < 4; ++ri)
                af[ri] = *(const bf16x8*)&hA[(ri * 16 + ln) * 72 + kk * 32 + quad * 8];
            #pragma unroll
            for (int oi = 0; oi < 4; ++oi)
                bfr[oi] = *(const bf16x8*)&hB[(w * 64 + oi * 16 + ln) * 72 + kk * 32 + quad * 8];
            #pragma unroll
            for (int ri = 0; ri < 4; ++ri)
                #pragma unroll
                for (int oi = 0; oi < 4; ++oi)
                    acc[ri][oi] = __builtin_amdgcn_mfma_f32_16x16x32_bf16(
                        af[ri], bfr[oi], acc[ri][oi], 0, 0, 0);
        }
        __syncthreads();
    }

    // stage acc -> hB as [o][n_local] (stride 72, conflict-light)
    #pragma unroll
    for (int ri = 0; ri < 4; ++ri) {
        const int n = ri * 16 + quad * 4;
        #pragma unroll
        for (int oi = 0; oi < 4; ++oi) {
            const int o = w * 64 + oi * 16 + ln;
            bf16x4 pv = {(__bf16)acc[ri][oi][0], (__bf16)acc[ri][oi][1],
                         (__bf16)acc[ri][oi][2], (__bf16)acc[ri][oi][3]};
            *(bf16x4*)&hB[o * 72 + n] = pv;
        }
    }
    __syncthreads();

    // whT writes: wave w covers o in [w*64, w*64+64); 8 rows x 128B per instr
    #pragma unroll
    for (int it = 0; it < 8; ++it) {
        const int o   = w * 64 + it * 8 + (l >> 3);
        const int seg = l & 7;
        const bf16x8 v = *(const bf16x8*)&hB[o * 72 + seg * 8];
        *(bf16x8*)&whT[((size_t)b * 256 + o) * 1024 + n0 + seg * 8] = v;
    }

    // fused si/sj: wave w sums o-range [w*64, w*64+64) for n = lane
    {
        float s1 = 0.f, s2 = 0.f;
        #pragma unroll 8
        for (int oi = 0; oi < 64; ++oi) {
            const int o = w * 64 + oi;
            const float v = (float)hB[o * 72 + l];
            s1 += v * a_g[o];
            s2 += v * a_g[256 + o];
        }
        red[w * 64 + l]       = s1;
        red[256 + w * 64 + l] = s2;
    }
    __syncthreads();
    if (t < 64) {
        si[b * 1024 + n0 + t] = red[t] + red[64 + t] + red[128 + t] + red[192 + t];
    } else if (t < 128) {
        const int n = t - 64;
        sj[b * 1024 + n0 + n] = red[256 + n] + red[320 + n] + red[384 + n] + red[448 + n];
    }
}

// ---------------- k3: fused attention ----------------
// grid (16, 32), 256 thr (4 waves). Software-pipelined j-loop.
__global__ __launch_bounds__(256) void k3_attn(const u64* __restrict__ mask,
                                               const __bf16* __restrict__ whT,
                                               const float* __restrict__ si_g,
                                               const float* __restrict__ sj_g,
                                               float* __restrict__ out) {
    __shared__ __bf16 lds_w[256 * 72];
    __shared__ __bf16 lds_s[64 * 72];
    __shared__ float  lds_denom[64];
    const int t    = threadIdx.x;
    const int b    = blockIdx.y;
    const int i0   = blockIdx.x * 64;
    const int w    = t >> 6;
    const int l    = t & 63;
    const int ln   = l & 15;
    const int quad = l >> 4;
    const int g    = t >> 4;   // 0..15
    const int j4   = t & 15;   // 0..15

    float si_r[4];
    #pragma unroll
    for (int m = 0; m < 4; ++m) si_r[m] = si_g[b * 1024 + i0 + m * 16 + g];

    float dsum[4] = {0.f, 0.f, 0.f, 0.f};
    f32x4 acc[4][4] = {};
    const __bf16* whTb  = whT + (size_t)b * 256 * 1024;
    const u64*    maskb = mask + ((size_t)b * 1024) * 16;

    // pipeline registers
    bf16x8 vreg[8];
    u64    msk[4];
    float4 sjv;

    // preload chunk 0
    #pragma unroll
    for (int it = 0; it < 8; ++it)
        vreg[it] = *(const bf16x8*)&whTb[(size_t)(it * 32 + (t >> 3)) * 1024 + (t & 7) * 8];
    #pragma unroll
    for (int m = 0; m < 4; ++m) msk[m] = maskb[(size_t)(i0 + m * 16 + g) * 16];
    sjv = *(const float4*)&sj_g[b * 1024 + j4 * 4];

    for (int jc = 0; jc < 16; ++jc) {
        const int j0 = jc * 64;
        // commit staged whT chunk to LDS
        #pragma unroll
        for (int it = 0; it < 8; ++it)
            *(bf16x8*)&lds_w[(it * 32 + (t >> 3)) * 72 + (t & 7) * 8] = vreg[it];
        // S tile: w = adj ? exp(leakyrelu(si+sj)) : 0
        #pragma unroll
        for (int m = 0; m < 4; ++m) {
            const int il   = m * 16 + g;
            const unsigned bits = (unsigned)(msk[m] >> (4 * j4)) & 0xFu;
            float e0 = si_r[m] + sjv.x; e0 = e0 > 0.f ? e0 : ALPHA * e0;
            float e1 = si_r[m] + sjv.y; e1 = e1 > 0.f ? e1 : ALPHA * e1;
            float e2 = si_r[m] + sjv.z; e2 = e2 > 0.f ? e2 : ALPHA * e2;
            float e3 = si_r[m] + sjv.w; e3 = e3 > 0.f ? e3 : ALPHA * e3;
            const float w0 = (bits & 1u) ? __expf(e0) : 0.f;
            const float w1 = (bits & 2u) ? __expf(e1) : 0.f;
            const float w2 = (bits & 4u) ? __expf(e2) : 0.f;
            const float w3 = (bits & 8u) ? __expf(e3) : 0.f;
            bf16x4 pv = {(__bf16)w0, (__bf16)w1, (__bf16)w2, (__bf16)w3};
            dsum[m] += (float)pv[0] + (float)pv[1] + (float)pv[2] + (float)pv[3];
            *(bf16x4*)&lds_s[il * 72 + j4 * 4] = pv;
        }
        __syncthreads();
        // prefetch chunk jc+1 while MFMA runs
        if (jc < 15) {
            const int j1 = j0 + 64;
            #pragma unroll
            for (int it = 0; it < 8; ++it)
                vreg[it] = *(const bf16x8*)&whTb[(size_t)(it * 32 + (t >> 3)) * 1024 + j1 + (t & 7) * 8];
            #pragma unroll
            for (int m = 0; m < 4; ++m)
                msk[m] = maskb[(size_t)(i0 + m * 16 + g) * 16 + jc + 1];
            sjv = *(const float4*)&sj_g[b * 1024 + j1 + j4 * 4];
        }
        // P(64x64) @ Wh(64x256)
        #pragma unroll
        for (int kk = 0; kk < 2; ++kk) {
            bf16x8 af[4], bfr[4];
            #pragma unroll
            for (int ri = 0; ri < 4; ++ri)
                af[ri] = *(const bf16x8*)&lds_s[(ri * 16 + ln) * 72 + kk * 32 + quad * 8];
            #pragma unroll
            for (int oi = 0; oi < 4; ++oi)
                bfr[oi] = *(const bf16x8*)&lds_w[(w * 64 + oi * 16 + ln) * 72 + kk * 32 + quad * 8];
            #pragma unroll
            for (int ri = 0; ri < 4; ++ri)
                #pragma unroll
                for (int oi = 0; oi < 4; ++oi)
                    acc[ri][oi] = __builtin_amdgcn_mfma_f32_16x16x32_bf16(
                        af[ri], bfr[oi], acc[ri][oi], 0, 0, 0);
        }
        __syncthreads();
    }

    // reduce denominators across the 16 j4 lanes per row
    #pragma unroll
    for (int m = 0; m < 4; ++m) {
        float v = dsum[m];
        v += __shfl_xor(v, 1);
        v += __shfl_xor(v, 2);
        v += __shfl_xor(v, 4);
        v += __shfl_xor(v, 8);
        if (j4 == 0) lds_denom[m * 16 + g] = v;
    }
    __syncthreads();
    // epilogue: normalize, ELU, store
    #pragma unroll
    for (int ri = 0; ri < 4; ++ri) {
        #pragma unroll
        for (int q = 0; q < 4; ++q) {
            const int il = ri * 16 + quad * 4 + q;
            const float dinv = 1.0f / fmaxf(lds_denom[il], 1e-30f);
            #pragma unroll
            for (int oi = 0; oi < 4; ++oi) {
                const int o = w * 64 + oi * 16 + ln;
                const float v = acc[ri][oi][q] * dinv;
                const float r = v > 0.f ? v : __expf(v) - 1.f;
                out[((size_t)(b * 1024 + i0 + il)) * 256 + o] = r;
            }
        }
    }
}

extern "C" void kernel_launch(void* const* d_in, const int* in_sizes, int n_in,
                              void* d_out, int out_size, void* d_ws, size_t ws_size,
                              hipStream_t stream) {
    const float* h   = (const float*)d_in[0];
    const int*   adj = (const int*)d_in[1];
    const float* W   = (const float*)d_in[2];
    const float* a   = (const float*)d_in[3];
    float* out = (float*)d_out;

    __bf16* whT  = (__bf16*)d_ws;                                   // 16 MiB
    float*  si   = (float*)((char*)d_ws + (size_t)16777216);        // 128 KiB
    float*  sj   = (float*)((char*)d_ws + (size_t)16777216 + 131072);
    u64*    mask = (u64*)((char*)d_ws + (size_t)16777216 + 262144); // 4 MiB

    k0_mask<<<2048, 256, 0, stream>>>(adj, mask);
    k1_gemm1<<<512, 256, 0, stream>>>(h, W, a, whT, si, sj);
    k3_attn<<<dim3(16, 32), 256, 0, stream>>>(mask, whT, si, sj, out);
}